// Round 4
// baseline (1079.816 us; speedup 1.0000x reference)
//
#include <hip/hip_runtime.h>

// AntisymmetricRNN forward: 999 sequential steps of x += 0.01*tanh(A@x + by),
// A = triu(W,1) - triu(W,1)^T - 0.001*I. One batch column per workgroup (256 WGs
// = 1/CU); all sync is intra-CU __syncthreads. FP32 throughout: the dynamics are
// norm-preserving (antisymmetric), so f16 rounding of A or x accumulates without
// decay (round-3 post-mortem: f16 path drifted to absmax 1.58 vs 0.11 threshold).
//
// Layout: 256 threads/WG. g = tid>>2 (row group), s = tid&3 (col segment).
// Lane holds A rows [4g,4g+4) x cols [64s,64s+64) in 256 fp32 VGPRs (float2
// pairs -> v_pk_fma_f32 eligible). x exchanged per step via fp32 LDS (2 KB,
// double-buffered). Per-row partials reduced across the quad with a 2-round DPP
// butterfly; lane tid owns row tid. Chunk rotation p=(j+2s)&15 makes the quad's
// broadcast ds_read_b128 hit bank groups {4j,4j+8,4j+16,4j+24}%32: conflict-free.

typedef float f2 __attribute__((ext_vector_type(2)));

template <int CTRL>
__device__ __forceinline__ float dpp_mov(float v) {
  return __builtin_bit_cast(float,
      __builtin_amdgcn_update_dpp(0, __builtin_bit_cast(int, v), CTRL, 0xF, 0xF, true));
}

__global__ __launch_bounds__(256, 1)
void arnn_kernel(const float* __restrict__ X0, const float* __restrict__ W,
                 const float* __restrict__ by, float* __restrict__ out) {
  const int tid = (int)threadIdx.x;
  const int bb  = (int)blockIdx.x;
  const int g = tid >> 2;
  const int s = tid & 3;

  __shared__ __align__(16) float xb[2][256];  // double-buffered x, fp32

  // ---- Prologue: A fragments in registers, fp32. Slot j holds physical chunk
  // p=(j+2s)&15 (4 cols each); two float2 per chunk.
  f2 a2[4][32];
#pragma unroll
  for (int i = 0; i < 4; ++i) {
    const int r = 4 * g + i;
#pragma unroll
    for (int j = 0; j < 16; ++j) {
      const int p = (j + 2 * s) & 15;
#pragma unroll
      for (int h = 0; h < 2; ++h) {
        const int c0 = 64 * s + 4 * p + 2 * h;
        const int c1 = c0 + 1;
        const float w0 = W[(c0 > r) ? (r * 256 + c0) : (c0 * 256 + r)];
        const float w1 = W[(c1 > r) ? (r * 256 + c1) : (c1 * 256 + r)];
        f2 t2;
        t2[0] = (c0 == r) ? -0.001f : ((c0 > r) ? w0 : -w0);
        t2[1] = (c1 == r) ? -0.001f : ((c1 > r) ? w1 : -w1);
        a2[i][2 * j + h] = t2;
      }
    }
  }

  const float byr = by[tid];
  float xm = X0[bb * 256 + tid];           // fp32 master state for row tid
  float* pout = out + (size_t)bb * 256000 + tid;
  *pout = xm;                               // t = 0 output = X0
  pout += 256;
  xb[1][tid] = xm;                          // iteration t=1 reads buffer (t&1)=1

  const bool s_b0 = (s & 1) != 0;
  const bool s_b1 = (s & 2) != 0;

#pragma unroll 1
  for (int t = 1; t < 1000; ++t) {
    __syncthreads();  // prev step's xb writes visible; prev reads done

    const float* xcur = &xb[t & 1][64 * s];
    f2 accA[4] = {{0.f,0.f},{0.f,0.f},{0.f,0.f},{0.f,0.f}};
    f2 accB[4] = {{0.f,0.f},{0.f,0.f},{0.f,0.f},{0.f,0.f}};

    // Two phases of 8 chunks: caps live x registers at 32 (VGPR pressure),
    // while each phase's reads are issued before its FMAs (latency hidden).
#pragma unroll
    for (int half = 0; half < 2; ++half) {
      int4 v[8];
#pragma unroll
      for (int j = 0; j < 8; ++j) {
        const int p = ((8 * half + j) + 2 * s) & 15;
        v[j] = *(const int4*)(xcur + 4 * p);
      }
#pragma unroll
      for (int j = 0; j < 8; ++j) {
        f2 xlo, xhi;
        xlo[0] = __builtin_bit_cast(float, v[j].x);
        xlo[1] = __builtin_bit_cast(float, v[j].y);
        xhi[0] = __builtin_bit_cast(float, v[j].z);
        xhi[1] = __builtin_bit_cast(float, v[j].w);
        const int jj = 8 * half + j;
#pragma unroll
        for (int i = 0; i < 4; ++i) {
          accA[i] = __builtin_elementwise_fma(a2[i][2 * jj],     xlo, accA[i]);
          accB[i] = __builtin_elementwise_fma(a2[i][2 * jj + 1], xhi, accB[i]);
        }
      }
    }

    const float p0 = (accA[0][0] + accB[0][0]) + (accA[0][1] + accB[0][1]);
    const float p1 = (accA[1][0] + accB[1][0]) + (accA[1][1] + accB[1][1]);
    const float p2 = (accA[2][0] + accB[2][0]) + (accA[2][1] + accB[2][1]);
    const float p3 = (accA[3][0] + accB[3][0]) + (accA[3][1] + accB[3][1]);

    // Quad butterfly reduce across s (in-register, DPP).
    // Round 1: partner s^1 (quad_perm [1,0,3,2] = 0xB1), keep rows with bit0==s0.
    const float k0 = s_b0 ? p1 : p0;
    const float k1 = s_b0 ? p3 : p2;
    const float g0 = s_b0 ? p0 : p1;
    const float g1 = s_b0 ? p2 : p3;
    const float n0 = k0 + dpp_mov<0xB1>(g0);
    const float n1 = k1 + dpp_mov<0xB1>(g1);
    // Round 2: partner s^2 (quad_perm [2,3,0,1] = 0x4E), keep row with bit1==s1.
    const float k2 = s_b1 ? n1 : n0;
    const float g2 = s_b1 ? n0 : n1;
    float y = k2 + dpp_mov<0x4E>(g2) + byr;  // full dot for row tid

    // tanh(y) = 1 - 2/(exp2(2*log2e*y)+1); inf-safe at both tails.
    const float e  = __builtin_amdgcn_exp2f(y * 2.8853900817779268f);
    const float th = 1.0f - 2.0f * __builtin_amdgcn_rcpf(e + 1.0f);
    xm = fmaf(0.01f, th, xm);

    *pout = xm;          // out[b][t][tid], coalesced per wave
    pout += 256;
    xb[(t + 1) & 1][tid] = xm;  // publish for next step
  }
}

extern "C" void kernel_launch(void* const* d_in, const int* in_sizes, int n_in,
                              void* d_out, int out_size, void* d_ws, size_t ws_size,
                              hipStream_t stream) {
  const float* X0 = (const float*)d_in[0];
  const float* W  = (const float*)d_in[1];
  const float* by = (const float*)d_in[2];
  float* out = (float*)d_out;
  (void)in_sizes; (void)n_in; (void)out_size; (void)d_ws; (void)ws_size;
  arnn_kernel<<<dim3(256), dim3(256), 0, stream>>>(X0, W, by, out);
}

// Round 6
// 838.565 us; speedup vs baseline: 1.2877x; 1.2877x over previous
//
#include <hip/hip_runtime.h>

// AntisymmetricRNN forward: 999 sequential steps of x += 0.01*tanh(A@x + by),
// A = triu(W,1) - triu(W,1)^T - 0.001*I. One batch column per workgroup (256 WGs
// = 1/CU). FP32 throughout (antisymmetric => norm-preserving dynamics; f16
// rounding of A or x integrates without decay -> fails threshold; round 3).
//
// Round-4 post-mortem: 4 rows x 64 cols/lane needed 256 VGPRs for A at 256
// threads -> compiler spilled ~half of A to scratch (VGPR_Count=172, FETCH 852MB,
// 38% VALUBusy, 2297 cy/step). This version: 512 threads/WG, 8 rows x 16 cols
// per lane -> A = 128 VGPRs, total ~190 < 256 cap (__launch_bounds__(512,2)).
// LDS traffic also halves (reuse 8 rows/lane): 4x ds_read_b128 per lane per step.
//
// Layout: g = tid>>4 (row group, rows [8g,8g+8)), s = tid&15 (cols [16s,16s+16)).
// Partials reduced over 16 lanes: ^1,^2 via DPP quad_perm; ^4,^8 via ds_swizzle.
// After reduction lane pair (s, s+8) both hold row r = 8g+(s&7): s<8 lane does
// the global store, s>=8 lane publishes to LDS — parallel epilogue.
// Chunk rotation p=(j+s)&3 spreads the quad-broadcast reads across banks.

typedef float f2 __attribute__((ext_vector_type(2)));

template <int CTRL>
__device__ __forceinline__ float dpp_mov(float v) {
  return __builtin_bit_cast(float,
      __builtin_amdgcn_update_dpp(0, __builtin_bit_cast(int, v), CTRL, 0xF, 0xF, true));
}

template <int PAT>
__device__ __forceinline__ float swz_xor(float v) {
  return __builtin_bit_cast(float,
      __builtin_amdgcn_ds_swizzle(__builtin_bit_cast(int, v), PAT));
}

__global__ __launch_bounds__(512, 2)
void arnn_kernel(const float* __restrict__ X0, const float* __restrict__ W,
                 const float* __restrict__ by, float* __restrict__ out) {
  const int tid = (int)threadIdx.x;
  const int bb  = (int)blockIdx.x;
  const int g = tid >> 4;   // row group: rows [8g, 8g+8)
  const int s = tid & 15;   // col segment: cols [16s, 16s+16)

  __shared__ __align__(16) float xb[2][256];  // double-buffered x, fp32

  // ---- Prologue: A fragments in registers. Slot j holds physical chunk
  // p=(j+s)&3 (4 cols each = 2 float2). One-time cost; W is L2-resident.
  f2 a2[8][8];
#pragma unroll
  for (int i = 0; i < 8; ++i) {
    const int r = 8 * g + i;
#pragma unroll
    for (int j = 0; j < 4; ++j) {
      const int p = (j + s) & 3;
#pragma unroll
      for (int h = 0; h < 2; ++h) {
        const int c0 = 16 * s + 4 * p + 2 * h;
        const int c1 = c0 + 1;
        const float w0 = W[(c0 > r) ? (r * 256 + c0) : (c0 * 256 + r)];
        const float w1 = W[(c1 > r) ? (r * 256 + c1) : (c1 * 256 + r)];
        f2 t2;
        t2[0] = (c0 == r) ? -0.001f : ((c0 > r) ? w0 : -w0);
        t2[1] = (c1 == r) ? -0.001f : ((c1 > r) ? w1 : -w1);
        a2[i][2 * j + h] = t2;
      }
    }
  }

  const int row = 8 * g + (s & 7);   // row this lane ends up owning (dup x2)
  const float byr = by[row];
  float xm = X0[bb * 256 + row];     // fp32 master state (duplicated in pair)
  const bool is_out_writer = (s < 8);
  float* pout = out + (size_t)bb * 256000 + row;
  if (is_out_writer) *pout = xm;     // t = 0 output = X0
  pout += 256;
  if (!is_out_writer) xb[1][row] = xm;  // t=1 reads buffer (t&1)=1

  const bool b0 = (s & 1) != 0;
  const bool b1 = (s & 2) != 0;
  const bool b2 = (s & 4) != 0;

#pragma unroll 1
  for (int t = 1; t < 1000; ++t) {
    __syncthreads();  // prev step's xb writes visible; prev reads done

    // Issue all 4 chunk reads (rotated addresses match A slot contents).
    const float* xcur = &xb[t & 1][16 * s];
    int4 v[4];
#pragma unroll
    for (int j = 0; j < 4; ++j) {
      const int p = (j + s) & 3;
      v[j] = *(const int4*)(xcur + 4 * p);
    }

    // 64 packed FMAs: 8 rows x 8 f2-cols. 8 independent chains, dep distance 8.
    f2 acc2[8] = {{0.f,0.f},{0.f,0.f},{0.f,0.f},{0.f,0.f},
                  {0.f,0.f},{0.f,0.f},{0.f,0.f},{0.f,0.f}};
#pragma unroll
    for (int j = 0; j < 4; ++j) {
      f2 xlo, xhi;
      xlo[0] = __builtin_bit_cast(float, v[j].x);
      xlo[1] = __builtin_bit_cast(float, v[j].y);
      xhi[0] = __builtin_bit_cast(float, v[j].z);
      xhi[1] = __builtin_bit_cast(float, v[j].w);
#pragma unroll
      for (int i = 0; i < 8; ++i) {
        acc2[i] = __builtin_elementwise_fma(a2[i][2 * j],     xlo, acc2[i]);
        acc2[i] = __builtin_elementwise_fma(a2[i][2 * j + 1], xhi, acc2[i]);
      }
    }
    float pr[8];
#pragma unroll
    for (int i = 0; i < 8; ++i) pr[i] = acc2[i][0] + acc2[i][1];

    // 4-round butterfly over the 16-lane segment group.
    // R1 (^1, quad_perm [1,0,3,2]): keep rows with bit0 == s bit0.
    float q[4];
#pragma unroll
    for (int k = 0; k < 4; ++k) {
      const float keep = b0 ? pr[2 * k + 1] : pr[2 * k];
      const float give = b0 ? pr[2 * k]     : pr[2 * k + 1];
      q[k] = keep + dpp_mov<0xB1>(give);
    }
    // R2 (^2, quad_perm [2,3,0,1]): keep rows with bit1 == s bit1.
    float r2[2];
#pragma unroll
    for (int m = 0; m < 2; ++m) {
      const float keep = b1 ? q[2 * m + 1] : q[2 * m];
      const float give = b1 ? q[2 * m]     : q[2 * m + 1];
      r2[m] = keep + dpp_mov<0x4E>(give);
    }
    // R3 (^4, ds_swizzle xor-4): keep row with bit2 == s bit2.
    {
      const float keep = b2 ? r2[1] : r2[0];
      const float give = b2 ? r2[0] : r2[1];
      r2[0] = keep + swz_xor<0x101F>(give);
    }
    // R4 (^8, ds_swizzle xor-8): width join; both pair lanes get the full dot.
    float y = r2[0] + swz_xor<0x201F>(r2[0]) + byr;

    // tanh(y) = 1 - 2/(exp2(2*log2e*y)+1); inf-safe at both tails.
    const float e  = __builtin_amdgcn_exp2f(y * 2.8853900817779268f);
    const float th = 1.0f - 2.0f * __builtin_amdgcn_rcpf(e + 1.0f);
    xm = fmaf(0.01f, th, xm);

    if (is_out_writer) {
      *pout = xm;                     // out[b][t][row]
    } else {
      xb[(t + 1) & 1][row] = xm;      // publish for next step
    }
    pout += 256;
  }
}

extern "C" void kernel_launch(void* const* d_in, const int* in_sizes, int n_in,
                              void* d_out, int out_size, void* d_ws, size_t ws_size,
                              hipStream_t stream) {
  const float* X0 = (const float*)d_in[0];
  const float* W  = (const float*)d_in[1];
  const float* by = (const float*)d_in[2];
  float* out = (float*)d_out;
  (void)in_sizes; (void)n_in; (void)out_size; (void)d_ws; (void)ws_size;
  arnn_kernel<<<dim3(256), dim3(512), 0, stream>>>(X0, W, by, out);
}

// Round 7
// 799.587 us; speedup vs baseline: 1.3505x; 1.0487x over previous
//
#include <hip/hip_runtime.h>

// AntisymmetricRNN forward: 999 sequential steps of x += 0.01*tanh(A@x + by),
// A = triu(W,1) - triu(W,1)^T - 0.001*I. One batch column per workgroup (256 WGs
// = 1/CU). FP32 throughout (antisymmetric => norm-preserving; f16 drifts, r3).
//
// r4/r6 post-mortem: compiler refuses to keep the 128-reg A fragment resident
// (r6: VGPR_Count=92 vs ~180 needed; FETCH 795MB of per-step reload traffic).
// Cause: backend occupancy-maximizing heuristic — __launch_bounds__ only sets
// the MIN waves/EU; scheduler still shrinks pressure chasing unusable occupancy
// (grid is 1 WG/CU). Fix: amdgpu_waves_per_eu(2,2) pins target occupancy = 2
// -> 256-VGPR budget, no motive to remat A. Validation: VGPR_Count >= 160,
// FETCH < 50MB.
//
// r6 also showed 9.8e7 LDS bank conflicts: p=(j+s)&3 put 4 lanes per bank
// group (addr 64s+16p -> group 16(s&1)+4p; s and s+4 collide). New rotation
// p=(j+(s>>1))&3 spreads even-s lanes 2-per-group (2-way = free, m136).
// Validation: SQ_LDS_BANK_CONFLICT < 5e6.
//
// Layout: 512 thr/WG. g=tid>>4 (rows [8g,8g+8)), s=tid&15 (cols [16s,16s+16)).
// A: 64 float2 = 128 VGPR/lane. x via fp32 LDS (2KB, double-buffered).
// Reduce over 16 lanes: ^1,^2 DPP quad_perm; ^4,^8 ds_swizzle. Lane pair
// (s, s+8) both own row 8g+(s&7): s<8 stores to global, s>=8 publishes to LDS.

typedef float f2 __attribute__((ext_vector_type(2)));

template <int CTRL>
__device__ __forceinline__ float dpp_mov(float v) {
  return __builtin_bit_cast(float,
      __builtin_amdgcn_update_dpp(0, __builtin_bit_cast(int, v), CTRL, 0xF, 0xF, true));
}

template <int PAT>
__device__ __forceinline__ float swz_xor(float v) {
  return __builtin_bit_cast(float,
      __builtin_amdgcn_ds_swizzle(__builtin_bit_cast(int, v), PAT));
}

__global__ __launch_bounds__(512)
__attribute__((amdgpu_waves_per_eu(2, 2)))
void arnn_kernel(const float* __restrict__ X0, const float* __restrict__ W,
                 const float* __restrict__ by, float* __restrict__ out) {
  const int tid = (int)threadIdx.x;
  const int bb  = (int)blockIdx.x;
  const int g = tid >> 4;   // row group: rows [8g, 8g+8)
  const int s = tid & 15;   // col segment: cols [16s, 16s+16)

  __shared__ __align__(16) float xb[2][256];  // double-buffered x, fp32

  // ---- Prologue: A fragments in registers. Slot j holds physical chunk
  // p=(j+(s>>1))&3 (4 cols = 2 float2). One-time cost; W is L2-resident.
  f2 a2[8][8];
#pragma unroll
  for (int i = 0; i < 8; ++i) {
    const int r = 8 * g + i;
#pragma unroll
    for (int j = 0; j < 4; ++j) {
      const int p = (j + (s >> 1)) & 3;
#pragma unroll
      for (int h = 0; h < 2; ++h) {
        const int c0 = 16 * s + 4 * p + 2 * h;
        const int c1 = c0 + 1;
        const float w0 = W[(c0 > r) ? (r * 256 + c0) : (c0 * 256 + r)];
        const float w1 = W[(c1 > r) ? (r * 256 + c1) : (c1 * 256 + r)];
        f2 t2;
        t2[0] = (c0 == r) ? -0.001f : ((c0 > r) ? w0 : -w0);
        t2[1] = (c1 == r) ? -0.001f : ((c1 > r) ? w1 : -w1);
        a2[i][2 * j + h] = t2;
      }
    }
  }

  const int row = 8 * g + (s & 7);   // row this lane ends up owning (dup x2)
  const float byr = by[row];
  float xm = X0[bb * 256 + row];     // fp32 master state (duplicated in pair)
  const bool is_out_writer = (s < 8);
  float* pout = out + (size_t)bb * 256000 + row;
  if (is_out_writer) *pout = xm;     // t = 0 output = X0
  pout += 256;
  if (!is_out_writer) xb[1][row] = xm;  // t=1 reads buffer (t&1)=1

  const bool b0 = (s & 1) != 0;
  const bool b1 = (s & 2) != 0;
  const bool b2 = (s & 4) != 0;

#pragma unroll 1
  for (int t = 1; t < 1000; ++t) {
    __syncthreads();  // prev step's xb writes visible; prev reads done

    // Issue all 4 chunk reads (rotated addresses match A slot contents).
    const float* xcur = &xb[t & 1][16 * s];
    int4 v[4];
#pragma unroll
    for (int j = 0; j < 4; ++j) {
      const int p = (j + (s >> 1)) & 3;
      v[j] = *(const int4*)(xcur + 4 * p);
    }

    // 64 packed FMAs: 8 rows x 8 f2-cols. 8 independent chains.
    f2 acc2[8] = {{0.f,0.f},{0.f,0.f},{0.f,0.f},{0.f,0.f},
                  {0.f,0.f},{0.f,0.f},{0.f,0.f},{0.f,0.f}};
#pragma unroll
    for (int j = 0; j < 4; ++j) {
      f2 xlo, xhi;
      xlo[0] = __builtin_bit_cast(float, v[j].x);
      xlo[1] = __builtin_bit_cast(float, v[j].y);
      xhi[0] = __builtin_bit_cast(float, v[j].z);
      xhi[1] = __builtin_bit_cast(float, v[j].w);
#pragma unroll
      for (int i = 0; i < 8; ++i) {
        acc2[i] = __builtin_elementwise_fma(a2[i][2 * j],     xlo, acc2[i]);
        acc2[i] = __builtin_elementwise_fma(a2[i][2 * j + 1], xhi, acc2[i]);
      }
    }
    float pr[8];
#pragma unroll
    for (int i = 0; i < 8; ++i) pr[i] = acc2[i][0] + acc2[i][1];

    // 4-round butterfly over the 16-lane segment group.
    // R1 (^1, quad_perm [1,0,3,2]): keep rows with bit0 == s bit0.
    float q[4];
#pragma unroll
    for (int k = 0; k < 4; ++k) {
      const float keep = b0 ? pr[2 * k + 1] : pr[2 * k];
      const float give = b0 ? pr[2 * k]     : pr[2 * k + 1];
      q[k] = keep + dpp_mov<0xB1>(give);
    }
    // R2 (^2, quad_perm [2,3,0,1]): keep rows with bit1 == s bit1.
    float r2[2];
#pragma unroll
    for (int m = 0; m < 2; ++m) {
      const float keep = b1 ? q[2 * m + 1] : q[2 * m];
      const float give = b1 ? q[2 * m]     : q[2 * m + 1];
      r2[m] = keep + dpp_mov<0x4E>(give);
    }
    // R3 (^4, ds_swizzle xor-4): keep row with bit2 == s bit2.
    {
      const float keep = b2 ? r2[1] : r2[0];
      const float give = b2 ? r2[0] : r2[1];
      r2[0] = keep + swz_xor<0x101F>(give);
    }
    // R4 (^8, ds_swizzle xor-8): width join; both pair lanes get the full dot.
    float y = r2[0] + swz_xor<0x201F>(r2[0]) + byr;

    // tanh(y) = 1 - 2/(exp2(2*log2e*y)+1); inf-safe at both tails.
    const float e  = __builtin_amdgcn_exp2f(y * 2.8853900817779268f);
    const float th = 1.0f - 2.0f * __builtin_amdgcn_rcpf(e + 1.0f);
    xm = fmaf(0.01f, th, xm);

    if (is_out_writer) {
      *pout = xm;                     // out[b][t][row]
    } else {
      xb[(t + 1) & 1][row] = xm;      // publish for next step
    }
    pout += 256;
  }
}

extern "C" void kernel_launch(void* const* d_in, const int* in_sizes, int n_in,
                              void* d_out, int out_size, void* d_ws, size_t ws_size,
                              hipStream_t stream) {
  const float* X0 = (const float*)d_in[0];
  const float* W  = (const float*)d_in[1];
  const float* by = (const float*)d_in[2];
  float* out = (float*)d_out;
  (void)in_sizes; (void)n_in; (void)out_size; (void)d_ws; (void)ws_size;
  arnn_kernel<<<dim3(256), dim3(512), 0, stream>>>(X0, W, by, out);
}